// Round 16
// baseline (382.813 us; speedup 1.0000x reference)
//
#include <hip/hip_runtime.h>
#include <hip/hip_bf16.h>

typedef __attribute__((ext_vector_type(4))) float f32x4;
typedef __attribute__((ext_vector_type(8))) short s16x8;
typedef unsigned long long u64;

namespace {
constexpr int B_   = 8192;
constexpr int NT   = 256;          // 4 waves; wave h = head h
constexpr int SPB  = 8;            // samples per block
constexpr int NBLK = B_ / SPB;     // 1024 blocks
// LDS layout
constexpr int XS_SH  = 48 * 136;                 // x staged bf16 [48][136] (rows 40..47 zero)
constexpr int RED_B  = XS_SH * 2;                // 13056: float redSQ[48][4][2]
constexpr int OUT_B  = RED_B + 48 * 4 * 2 * 4;   // 14592: float ost[40][132] (r then y)
constexpr int OSTR   = 132;                      // 16B-aligned row stride
constexpr int POOL_B = OUT_B + 40 * OSTR * 4;    // 35712 B -> 4 blocks/CU by LDS
}

__device__ __forceinline__ ushort f2b(float f) {
    union { __hip_bfloat16 h; ushort u; } cv;
    cv.h = __float2bfloat16(f);
    return cv.u;
}
// Cheap f32->bf16 pair: round-half-up on raw bits (verified R11, absmax
// 0.0078). Valid: no NaN/inf occurs; differs from RNE only on exact ties.
__device__ __forceinline__ unsigned bfpair(float x, float y) {
    const unsigned ux = __float_as_uint(x) + 0x8000u;
    const unsigned uy = __float_as_uint(y) + 0x8000u;
    return (ux >> 16) | (uy & 0xFFFF0000u);
}
__device__ __forceinline__ u64 pack4(f32x4 v) {
    return (u64)bfpair(v[0], v[1]) | ((u64)bfpair(v[2], v[3]) << 32);
}
__device__ __forceinline__ u64 pack4f(float4 v) {
    return (u64)bfpair(v.x, v.y) | ((u64)bfpair(v.z, v.w) << 32);
}
// Zero-cost fragment build (verified R10/R11): both MFMA operands share the
// slot->k bijection pi(lc,s) = {4lc+s, 16+4lc+s-4}; MFMA contraction is
// permutation-invariant when A and B share pi.
__device__ __forceinline__ s16x8 cat(u64 A, u64 B) {
    union { u64 q[2]; s16x8 v; } r;
    r.q[0] = A; r.q[1] = B;
    return r.v;
}
#define MFMA(a, b, c) __builtin_amdgcn_mfma_f32_16x16x32_bf16((a), (b), (c), 0, 0, 0)

// Wt[m][n][k] = W_m[k][n] bf16 (full RNE, one-time). m 0..3: Wq[m] (m=0
// doubles as key matrix per merge='no' quirk); m=4: Wv; m=5: Wr.  192 KB.
__global__ void convert_w(const float* __restrict__ Wq,
                          const float* __restrict__ Wv,
                          const float* __restrict__ Wr,
                          ushort* __restrict__ Wt)
{
    int idx = blockIdx.x * 256 + threadIdx.x;
    if (idx >= 6 * 16384) return;
    int m = idx >> 14, r = idx & 16383, n = r >> 7, k = r & 127;
    float v;
    if (m < 4)       v = Wq[(size_t)m * 16384 + k * 128 + n];
    else if (m == 4) v = Wv[k * 128 + n];
    else             v = Wr[k * 128 + n];
    Wt[idx] = f2b(v);
}

// R16: minimal-register restructure targeting total <= 128 regs/wave
// (16 waves/CU, up from 8). vs R11: projections split into 4 SEQUENTIAL
// passes (one 24-reg acc block live at a time; R6 proved 96 concurrent
// accs spill); ar offloaded to ost after the r-pass (wave-local, R4-proven
// mechanism); xp prefetch dropped (-20 held regs; 4 waves/SIMD hide the
// stage latency instead). All numerics byte-identical to R11.
__global__ __launch_bounds__(NT, 4)
void mdr_fused18(const float* __restrict__ inputs,
                 const int* __restrict__ dom,
                 const ushort* __restrict__ Wt,
                 const float* __restrict__ ln_g,
                 const float* __restrict__ ln_b,
                 float* __restrict__ out)
{
    __shared__ __align__(16) char pool[POOL_B];
    ushort* sp = reinterpret_cast<ushort*>(pool);
    float* red = reinterpret_cast<float*>(pool + RED_B);
    float* ost = reinterpret_cast<float*>(pool + OUT_B);

    const int t = threadIdx.x;
    const int w = t >> 6, l = t & 63;
    const int lr = l & 15, lc = l >> 4;
    const int h = w;                       // wave = head
    const size_t s0 = (size_t)blockIdx.x * SPB;
    const float4* in4 = reinterpret_cast<const float4*>(inputs);
    float4* out4g = reinterpret_cast<float4*>(out);

    // zero XS pad rows 40..47 once (covered by first B1)
    {
        const int row = 40 + (t >> 5), c = (t & 31) * 4;
        *reinterpret_cast<u64*>(&sp[row * 136 + c]) = 0ull;
    }

    #pragma unroll 1
    for (int s = 0; s < SPB; ++s) {
        // ---- stage x -> XS (direct load, no held prefetch) ----
        #pragma unroll
        for (int j = 0; j < 5; ++j) {
            const int idx4 = t + 256 * j;
            const int row = idx4 >> 5, c4 = idx4 & 31;
            const float4 xv = in4[(s0 + s) * 1280 + idx4];
            *reinterpret_cast<u64*>(&sp[row * 136 + c4 * 4]) = pack4f(xv);
        }
        const int d = dom[s0 + s] - 1;
        __syncthreads();                                   // B1: XS ready
        // (B1 also fences ost/red reuse: read-pass(s-1) precedes stage(s)
        //  precedes B1(s) in every wave's program order; the r-pass below
        //  writes ost only after B1.)

        const ushort* wq = Wt + (size_t)d * 16384 + (h * 32) * 128;
        const ushort* wk = Wt + (h * 32) * 128;            // key = Wq[0]
        const ushort* wv = Wt + (size_t)4 * 16384 + (h * 32) * 128;
        const ushort* wr = Wt + (size_t)5 * 16384 + (h * 32) * 128;
        const int wo = lr * 128 + lc * 8;

        // ---- q-pass ----
        s16x8 qfr[3], kfr[3];
        {
            f32x4 aq[2][3];
            #pragma unroll
            for (int nt = 0; nt < 2; ++nt)
                #pragma unroll
                for (int rt = 0; rt < 3; ++rt)
                    aq[nt][rt] = f32x4{0.f, 0.f, 0.f, 0.f};
            #pragma unroll
            for (int kk = 0; kk < 4; ++kk) {
                s16x8 xf[3];
                #pragma unroll
                for (int rt = 0; rt < 3; ++rt)
                    xf[rt] = *reinterpret_cast<const s16x8*>(&sp[(rt * 16 + lr) * 136 + kk * 32 + lc * 8]);
                #pragma unroll
                for (int nt = 0; nt < 2; ++nt) {
                    const s16x8 qf = *reinterpret_cast<const s16x8*>(wq + nt * 2048 + wo + kk * 32);
                    #pragma unroll
                    for (int rt = 0; rt < 3; ++rt)
                        aq[nt][rt] = MFMA(qf, xf[rt], aq[nt][rt]);  // q^T: [n][xrow]
                }
            }
            #pragma unroll
            for (int tt = 0; tt < 3; ++tt)
                qfr[tt] = cat(pack4(aq[0][tt]), pack4(aq[1][tt]));
        }

        // ---- k-pass ----
        {
            f32x4 ak[2][3];
            #pragma unroll
            for (int nt = 0; nt < 2; ++nt)
                #pragma unroll
                for (int rt = 0; rt < 3; ++rt)
                    ak[nt][rt] = f32x4{0.f, 0.f, 0.f, 0.f};
            #pragma unroll
            for (int kk = 0; kk < 4; ++kk) {
                s16x8 xf[3];
                #pragma unroll
                for (int rt = 0; rt < 3; ++rt)
                    xf[rt] = *reinterpret_cast<const s16x8*>(&sp[(rt * 16 + lr) * 136 + kk * 32 + lc * 8]);
                #pragma unroll
                for (int nt = 0; nt < 2; ++nt) {
                    const s16x8 kf = *reinterpret_cast<const s16x8*>(wk + nt * 2048 + wo + kk * 32);
                    #pragma unroll
                    for (int rt = 0; rt < 3; ++rt)
                        ak[nt][rt] = MFMA(kf, xf[rt], ak[nt][rt]);  // k^T
                }
            }
            #pragma unroll
            for (int tt = 0; tt < 3; ++tt)
                kfr[tt] = cat(pack4(ak[0][tt]), pack4(ak[1][tt]));
        }

        // ---- v-pass ----
        u64 pkV[3][2];
        {
            f32x4 av[3][2];
            #pragma unroll
            for (int rt = 0; rt < 3; ++rt)
                #pragma unroll
                for (int nt = 0; nt < 2; ++nt)
                    av[rt][nt] = f32x4{0.f, 0.f, 0.f, 0.f};
            #pragma unroll
            for (int kk = 0; kk < 4; ++kk) {
                s16x8 xf[3];
                #pragma unroll
                for (int rt = 0; rt < 3; ++rt)
                    xf[rt] = *reinterpret_cast<const s16x8*>(&sp[(rt * 16 + lr) * 136 + kk * 32 + lc * 8]);
                #pragma unroll
                for (int nt = 0; nt < 2; ++nt) {
                    const s16x8 vf = *reinterpret_cast<const s16x8*>(wv + nt * 2048 + wo + kk * 32);
                    #pragma unroll
                    for (int rt = 0; rt < 3; ++rt)
                        av[rt][nt] = MFMA(xf[rt], vf, av[rt][nt]);  // v: [xrow][e]
                }
            }
            #pragma unroll
            for (int rt = 0; rt < 3; ++rt)
                #pragma unroll
                for (int nt = 0; nt < 2; ++nt)
                    pkV[rt][nt] = pack4(av[rt][nt]);
        }

        // ---- r-pass -> offload to ost (frees 24 regs for QK/PV phases;
        //      wave-local addresses, mechanism correctness-proven in R4) ----
        {
            f32x4 arr[2][3];
            #pragma unroll
            for (int nt = 0; nt < 2; ++nt)
                #pragma unroll
                for (int rt = 0; rt < 3; ++rt)
                    arr[nt][rt] = f32x4{0.f, 0.f, 0.f, 0.f};
            #pragma unroll
            for (int kk = 0; kk < 4; ++kk) {
                s16x8 xf[3];
                #pragma unroll
                for (int rt = 0; rt < 3; ++rt)
                    xf[rt] = *reinterpret_cast<const s16x8*>(&sp[(rt * 16 + lr) * 136 + kk * 32 + lc * 8]);
                #pragma unroll
                for (int nt = 0; nt < 2; ++nt) {
                    const s16x8 rf = *reinterpret_cast<const s16x8*>(wr + nt * 2048 + wo + kk * 32);
                    #pragma unroll
                    for (int rt = 0; rt < 3; ++rt)
                        arr[nt][rt] = MFMA(rf, xf[rt], arr[nt][rt]);  // r^T
                }
            }
            #pragma unroll
            for (int rt = 0; rt < 3; ++rt) {
                if (rt == 2 && lr >= 8) continue;          // rows >= 40
                #pragma unroll
                for (int nt = 0; nt < 2; ++nt) {
                    float4 rv;
                    rv.x = arr[nt][rt][0]; rv.y = arr[nt][rt][1];
                    rv.z = arr[nt][rt][2]; rv.w = arr[nt][rt][3];
                    *reinterpret_cast<float4*>(&ost[(rt * 16 + lr) * OSTR + h * 32 + nt * 16 + 4 * lc]) = rv;
                }
            }
        }

        // ---- QK^T fused with softmax per it-row block ----
        // S^T[j][i] = mfma(A=k, B=q); pi cancels. C-layout HW-fixed:
        // lane holds S[i=it*16+lr][j=jt*16+4lc+reg]
        const float scale = 0.17677669529663689f;   // 1/sqrt(32)
        u64 pkP[3][3];
        float inv[3];
        #pragma unroll
        for (int it = 0; it < 3; ++it) {
            f32x4 sr[3];
            #pragma unroll
            for (int jt = 0; jt < 3; ++jt) {
                f32x4 z = {0.f, 0.f, 0.f, 0.f};
                sr[jt] = MFMA(kfr[jt], qfr[it], z);
            }
            float sum = 0.f;
            #pragma unroll
            for (int jt = 0; jt < 3; ++jt) {
                f32x4 pv;
                #pragma unroll
                for (int reg = 0; reg < 4; ++reg) {
                    float p = (jt == 2 && lc >= 2) ? 0.f : __expf(sr[jt][reg] * scale);  // mask j>=40
                    pv[reg] = p;
                    sum += p;
                }
                pkP[it][jt] = pack4(pv);
            }
            sum += __shfl_xor(sum, 16);
            sum += __shfl_xor(sum, 32);
            inv[it] = 1.f / sum;           // folded into epilogue (P unnormalized)
        }

        // ---- PV, transposed: O^T[e][i] = mfma(A=v^T, B=P) ----
        // kk=1 pads slots with zeros on BOTH operands — pairing stays exact.
        f32x4 o[2][3];
        #pragma unroll
        for (int et = 0; et < 2; ++et)
            #pragma unroll
            for (int it = 0; it < 3; ++it)
                o[et][it] = f32x4{0.f, 0.f, 0.f, 0.f};
        #pragma unroll
        for (int kk = 0; kk < 2; ++kk) {
            s16x8 vfr[2], pfr[3];
            #pragma unroll
            for (int et = 0; et < 2; ++et)
                vfr[et] = kk ? cat(pkV[2][et], 0ull)
                             : cat(pkV[0][et], pkV[1][et]);
            #pragma unroll
            for (int it = 0; it < 3; ++it)
                pfr[it] = kk ? cat(pkP[it][2], 0ull)
                             : cat(pkP[it][0], pkP[it][1]);
            #pragma unroll
            for (int et = 0; et < 2; ++et)
                #pragma unroll
                for (int it = 0; it < 3; ++it)
                    o[et][it] = MFMA(vfr[et], pfr[it], o[et][it]);
        }

        // ---- epilogue: y = relu(o*inv + r[ost]); LN partials; y -> ost ----
        #pragma unroll
        for (int it = 0; it < 3; ++it) {
            const bool valid = !(it == 2 && lr >= 8);      // rows < 40
            float sa = 0.f, qa2 = 0.f;
            float4 yv[2];
            #pragma unroll
            for (int et = 0; et < 2; ++et) {
                float4 rv = valid
                    ? *reinterpret_cast<const float4*>(&ost[(it * 16 + lr) * OSTR + h * 32 + et * 16 + 4 * lc])
                    : make_float4(0.f, 0.f, 0.f, 0.f);
                #pragma unroll
                for (int reg = 0; reg < 4; ++reg) {
                    float yy = fmaxf(fmaf(o[et][it][reg], inv[it], (&rv.x)[reg]), 0.f);
                    (&yv[et].x)[reg] = yy;
                    sa += yy;
                    qa2 = fmaf(yy, yy, qa2);
                }
            }
            sa  += __shfl_xor(sa, 16);   sa  += __shfl_xor(sa, 32);
            qa2 += __shfl_xor(qa2, 16);  qa2 += __shfl_xor(qa2, 32);
            if (lc == 0)
                *reinterpret_cast<float2*>(&red[((it * 16 + lr) * 4 + w) * 2]) =
                    make_float2(sa, qa2);
            if (valid) {
                #pragma unroll
                for (int et = 0; et < 2; ++et)
                    *reinterpret_cast<float4*>(&ost[(it * 16 + lr) * OSTR + h * 32 + et * 16 + 4 * lc]) = yv[et];
            }
        }
        __syncthreads();                                   // B2: red + ost ready

        // ---- read-pass: stats from red (broadcast), LN affine, coalesced store ----
        const int c4r = t & 31;
        const float4 gvr = *reinterpret_cast<const float4*>(&ln_g[d * 128 + c4r * 4]);
        const float4 bvr = *reinterpret_cast<const float4*>(&ln_b[d * 128 + c4r * 4]);
        const size_t b4 = (s0 + s) * 1280;
        #pragma unroll
        for (int j5 = 0; j5 < 5; ++j5) {
            const int idx = j5 * 256 + t;
            const int row = idx >> 5;                      // (idx & 31) == c4r
            const float4 r01 = *reinterpret_cast<const float4*>(&red[row * 8]);
            const float4 r23 = *reinterpret_cast<const float4*>(&red[row * 8 + 4]);
            const float sa = r01.x + r01.z + r23.x + r23.z;
            const float q2 = r01.y + r01.w + r23.y + r23.w;
            const float mean = sa * (1.f / 128.f);
            const float rstd = rsqrtf(q2 * (1.f / 128.f) - mean * mean + 1e-6f);
            const float4 v = *reinterpret_cast<const float4*>(&ost[row * OSTR + c4r * 4]);
            float4 ov;
            ov.x = (v.x - mean) * rstd * gvr.x + bvr.x;
            ov.y = (v.y - mean) * rstd * gvr.y + bvr.y;
            ov.z = (v.z - mean) * rstd * gvr.z + bvr.z;
            ov.w = (v.w - mean) * rstd * gvr.w + bvr.w;
            out4g[b4 + idx] = ov;
        }
    }
}

extern "C" void kernel_launch(void* const* d_in, const int* in_sizes, int n_in,
                              void* d_out, int out_size, void* d_ws, size_t ws_size,
                              hipStream_t stream)
{
    const float* inputs = (const float*)d_in[0];
    const int*   dm     = (const int*)d_in[1];
    const float* Wq     = (const float*)d_in[2];
    const float* Wv     = (const float*)d_in[3];
    const float* Wr     = (const float*)d_in[4];
    const float* g      = (const float*)d_in[5];
    const float* bt     = (const float*)d_in[6];
    float* outp         = (float*)d_out;
    ushort* Wt          = (ushort*)d_ws;   // 6*128*128*2 = 192 KB

    convert_w<<<(6 * 16384 + 255) / 256, 256, 0, stream>>>(Wq, Wv, Wr, Wt);
    mdr_fused18<<<NBLK, NT, 0, stream>>>(inputs, dm, Wt, g, bt, outp);
}

// Round 17
// 133.465 us; speedup vs baseline: 2.8683x; 2.8683x over previous
//
#include <hip/hip_runtime.h>
#include <hip/hip_bf16.h>

typedef __attribute__((ext_vector_type(4))) float f32x4;
typedef __attribute__((ext_vector_type(8))) short s16x8;
typedef unsigned long long u64;

namespace {
constexpr int B_   = 8192;
constexpr int NT   = 256;          // 4 waves; wave h = head h
constexpr int SPB  = 8;            // samples per block (R5-proven)
constexpr int NBLK = B_ / SPB;     // 1024 blocks
// LDS layout
constexpr int XS_SH  = 48 * 136;                 // x staged bf16 [48][136] (rows 40..47 zero)
constexpr int RED_B  = XS_SH * 2;                // 13056: float redSQ[48][4][2]
constexpr int OUT_B  = RED_B + 48 * 4 * 2 * 4;   // 14592: float ost[40][132]
constexpr int OSTR   = 132;                      // 16B-aligned row stride
constexpr int POOL_B = OUT_B + 40 * OSTR * 4;    // 35712 B
}

__device__ __forceinline__ ushort f2b(float f) {
    union { __hip_bfloat16 h; ushort u; } cv;
    cv.h = __float2bfloat16(f);
    return cv.u;
}
// Cheap f32->bf16 pair: round-half-up on raw bits (verified R11, absmax
// 0.0078). Valid because no NaN/inf can occur in this kernel's data;
// differs from RNE only on exact-tie mantissas (1 ulp, measure-zero).
__device__ __forceinline__ unsigned bfpair(float x, float y) {
    const unsigned ux = __float_as_uint(x) + 0x8000u;
    const unsigned uy = __float_as_uint(y) + 0x8000u;
    return (ux >> 16) | (uy & 0xFFFF0000u);
}
__device__ __forceinline__ u64 pack4(f32x4 v) {
    return (u64)bfpair(v[0], v[1]) | ((u64)bfpair(v[2], v[3]) << 32);
}
__device__ __forceinline__ u64 pack4f(float4 v) {
    return (u64)bfpair(v.x, v.y) | ((u64)bfpair(v.z, v.w) << 32);
}
// Zero-cost fragment build (verified R10/R11): both MFMA operands share the
// slot->k bijection pi(lc,s) = {4lc+s, 16+4lc+s-4}; MFMA contraction is
// permutation-invariant when A and B share pi.
__device__ __forceinline__ s16x8 cat(u64 A, u64 B) {
    union { u64 q[2]; s16x8 v; } r;
    r.q[0] = A; r.q[1] = B;
    return r.v;
}
#define MFMA(a, b, c) __builtin_amdgcn_mfma_f32_16x16x32_bf16((a), (b), (c), 0, 0, 0)

// Wt[m][n][k] = W_m[k][n] bf16 (full RNE — one-time cost, keeps weight
// accuracy max). m 0..3: Wq[m] (m=0 doubles as key matrix per merge='no'
// quirk); m=4: Wv; m=5: Wr.  192 KB total.
__global__ void convert_w(const float* __restrict__ Wq,
                          const float* __restrict__ Wv,
                          const float* __restrict__ Wr,
                          ushort* __restrict__ Wt)
{
    int idx = blockIdx.x * 256 + threadIdx.x;
    if (idx >= 6 * 16384) return;
    int m = idx >> 14, r = idx & 16383, n = r >> 7, k = r & 127;
    float v;
    if (m < 4)       v = Wq[(size_t)m * 16384 + k * 128 + n];
    else if (m == 4) v = Wv[k * 128 + n];
    else             v = Wr[k * 128 + n];
    Wt[idx] = f2b(v);
}

// FINAL (session best, 133.2 us vs 218.6 baseline). (NT,2): cap 256 total
// regs/wave — the ONLY no-spill regime for this algorithm (total live state
// ~250; caps of 128/170 spilled in 5 separate attempts). Structure: 2-pass
// projections, pi-concat fragments (no shuffle remap), cheap bf16 pack,
// fused per-it QK+softmax, coalesced staged output with 2 barriers/sample.
// Occupancy is register-file-capped at 2 waves/SIMD; schedule alternatives
// (setprio, lgkm-only barriers, single-barrier double-buffering) measured
// null or negative (R12-R15).
__global__ __launch_bounds__(NT, 2)
void mdr_fused13(const float* __restrict__ inputs,
                 const int* __restrict__ dom,
                 const ushort* __restrict__ Wt,
                 const float* __restrict__ ln_g,
                 const float* __restrict__ ln_b,
                 float* __restrict__ out)
{
    __shared__ __align__(16) char pool[POOL_B];
    ushort* sp = reinterpret_cast<ushort*>(pool);
    float* red = reinterpret_cast<float*>(pool + RED_B);
    float* ost = reinterpret_cast<float*>(pool + OUT_B);

    const int t = threadIdx.x;
    const int w = t >> 6, l = t & 63;
    const int lr = l & 15, lc = l >> 4;
    const int h = w;                       // wave = head
    const size_t s0 = (size_t)blockIdx.x * SPB;
    const float4* in4 = reinterpret_cast<const float4*>(inputs);
    float4* out4g = reinterpret_cast<float4*>(out);

    // zero XS pad rows 40..47 once (covered by first B1)
    {
        const int row = 40 + (t >> 5), c = (t & 31) * 4;
        *reinterpret_cast<u64*>(&sp[row * 136 + c]) = 0ull;
    }

    float4 xp[5];
    #pragma unroll
    for (int j = 0; j < 5; ++j)
        xp[j] = in4[s0 * 1280 + t + 256 * j];

    #pragma unroll 1
    for (int s = 0; s < SPB; ++s) {
        // ---- stage x -> XS (bf16, cheap pack) ----
        #pragma unroll
        for (int j = 0; j < 5; ++j) {
            const int idx4 = t + 256 * j;
            const int row = idx4 >> 5, c4 = idx4 & 31;
            *reinterpret_cast<u64*>(&sp[row * 136 + c4 * 4]) = pack4f(xp[j]);
        }
        const int d = dom[s0 + s] - 1;
        __syncthreads();                                   // B1: XS ready
        // (B1 also fences ost/red reuse: read-pass(s-1) precedes stage(s)
        //  precedes B1(s) in every wave's program order.)

        const ushort* wq = Wt + (size_t)d * 16384 + (h * 32) * 128;
        const ushort* wk = Wt + (h * 32) * 128;            // key = Wq[0]
        const ushort* wv = Wt + (size_t)4 * 16384 + (h * 32) * 128;
        const ushort* wr = Wt + (size_t)5 * 16384 + (h * 32) * 128;
        const int wo = lr * 128 + lc * 8;

        // ---- pass 1: q, k projections ----
        f32x4 aq[2][3], ak[2][3];
        #pragma unroll
        for (int nt = 0; nt < 2; ++nt)
            #pragma unroll
            for (int rt = 0; rt < 3; ++rt) {
                aq[nt][rt] = f32x4{0.f, 0.f, 0.f, 0.f};
                ak[nt][rt] = f32x4{0.f, 0.f, 0.f, 0.f};
            }
        #pragma unroll
        for (int kk = 0; kk < 4; ++kk) {
            s16x8 xf[3];
            #pragma unroll
            for (int rt = 0; rt < 3; ++rt)
                xf[rt] = *reinterpret_cast<const s16x8*>(&sp[(rt * 16 + lr) * 136 + kk * 32 + lc * 8]);
            #pragma unroll
            for (int nt = 0; nt < 2; ++nt) {
                const int o = nt * 2048 + wo + kk * 32;
                const s16x8 qf = *reinterpret_cast<const s16x8*>(wq + o);
                const s16x8 kf = *reinterpret_cast<const s16x8*>(wk + o);
                #pragma unroll
                for (int rt = 0; rt < 3; ++rt) {
                    aq[nt][rt] = MFMA(qf, xf[rt], aq[nt][rt]);  // q^T: [n][xrow]
                    ak[nt][rt] = MFMA(kf, xf[rt], ak[nt][rt]);  // k^T
                }
            }
        }
        // pi-consistent fragments (q/k rows >= 40 exact zeros via XS padding)
        s16x8 qfr[3], kfr[3];
        #pragma unroll
        for (int tt = 0; tt < 3; ++tt) {
            qfr[tt] = cat(pack4(aq[0][tt]), pack4(aq[1][tt]));
            kfr[tt] = cat(pack4(ak[0][tt]), pack4(ak[1][tt]));
        }

        // ---- pass 2: v, r projections (ar stays in registers) ----
        f32x4 av[3][2], ar[2][3];
        #pragma unroll
        for (int nt = 0; nt < 2; ++nt)
            #pragma unroll
            for (int rt = 0; rt < 3; ++rt) {
                av[rt][nt] = f32x4{0.f, 0.f, 0.f, 0.f};
                ar[nt][rt] = f32x4{0.f, 0.f, 0.f, 0.f};
            }
        #pragma unroll
        for (int kk = 0; kk < 4; ++kk) {
            s16x8 xf[3];
            #pragma unroll
            for (int rt = 0; rt < 3; ++rt)
                xf[rt] = *reinterpret_cast<const s16x8*>(&sp[(rt * 16 + lr) * 136 + kk * 32 + lc * 8]);
            #pragma unroll
            for (int nt = 0; nt < 2; ++nt) {
                const int o = nt * 2048 + wo + kk * 32;
                const s16x8 vf = *reinterpret_cast<const s16x8*>(wv + o);
                const s16x8 rf = *reinterpret_cast<const s16x8*>(wr + o);
                #pragma unroll
                for (int rt = 0; rt < 3; ++rt) {
                    av[rt][nt] = MFMA(xf[rt], vf, av[rt][nt]);  // v: [xrow][e]
                    ar[nt][rt] = MFMA(rf, xf[rt], ar[nt][rt]);  // r^T
                }
            }
        }
        u64 pkV[3][2];
        #pragma unroll
        for (int rt = 0; rt < 3; ++rt)
            #pragma unroll
            for (int nt = 0; nt < 2; ++nt)
                pkV[rt][nt] = pack4(av[rt][nt]);

        // ---- QK^T fused with softmax per it-row block ----
        // S^T[j][i] = mfma(A=k, B=q); pi cancels. Output C-layout HW-fixed:
        // lane holds S[i=it*16+lr][j=jt*16+4lc+reg]
        const float scale = 0.17677669529663689f;   // 1/sqrt(32)
        u64 pkP[3][3];
        float inv[3];
        #pragma unroll
        for (int it = 0; it < 3; ++it) {
            f32x4 sr[3];
            #pragma unroll
            for (int jt = 0; jt < 3; ++jt) {
                f32x4 z = {0.f, 0.f, 0.f, 0.f};
                sr[jt] = MFMA(kfr[jt], qfr[it], z);
            }
            float sum = 0.f;
            #pragma unroll
            for (int jt = 0; jt < 3; ++jt) {
                f32x4 pv;
                #pragma unroll
                for (int reg = 0; reg < 4; ++reg) {
                    float p = (jt == 2 && lc >= 2) ? 0.f : __expf(sr[jt][reg] * scale);  // mask j>=40
                    pv[reg] = p;
                    sum += p;
                }
                pkP[it][jt] = pack4(pv);
            }
            sum += __shfl_xor(sum, 16);
            sum += __shfl_xor(sum, 32);
            inv[it] = 1.f / sum;           // folded into epilogue (P unnormalized)
        }

        // prefetch next sample (covered by PV..B2..read-pass)
        if (s + 1 < SPB) {
            #pragma unroll
            for (int j = 0; j < 5; ++j)
                xp[j] = in4[(s0 + s + 1) * 1280 + t + 256 * j];
        }

        // ---- PV, transposed: O^T[e][i] = mfma(A=v^T, B=P) ----
        // kk=1 pads slots with zeros on BOTH operands — pairing stays exact.
        f32x4 o[2][3];
        #pragma unroll
        for (int et = 0; et < 2; ++et)
            #pragma unroll
            for (int it = 0; it < 3; ++it)
                o[et][it] = f32x4{0.f, 0.f, 0.f, 0.f};
        #pragma unroll
        for (int kk = 0; kk < 2; ++kk) {
            s16x8 vfr[2], pfr[3];
            #pragma unroll
            for (int et = 0; et < 2; ++et)
                vfr[et] = kk ? cat(pkV[2][et], 0ull)
                             : cat(pkV[0][et], pkV[1][et]);
            #pragma unroll
            for (int it = 0; it < 3; ++it)
                pfr[it] = kk ? cat(pkP[it][2], 0ull)
                             : cat(pkP[it][0], pkP[it][1]);
            #pragma unroll
            for (int et = 0; et < 2; ++et)
                #pragma unroll
                for (int it = 0; it < 3; ++it)
                    o[et][it] = MFMA(vfr[et], pfr[it], o[et][it]);
        }

        // ---- epilogue: y = relu(o*inv + ar); LN partials; y -> ost ----
        #pragma unroll
        for (int it = 0; it < 3; ++it) {
            const bool valid = !(it == 2 && lr >= 8);      // rows < 40
            float sa = 0.f, qa2 = 0.f;
            float4 yv[2];
            #pragma unroll
            for (int et = 0; et < 2; ++et)
                #pragma unroll
                for (int reg = 0; reg < 4; ++reg) {
                    float yy = fmaxf(fmaf(o[et][it][reg], inv[it], ar[et][it][reg]), 0.f);
                    (&yv[et].x)[reg] = yy;
                    sa += yy;
                    qa2 = fmaf(yy, yy, qa2);
                }
            sa  += __shfl_xor(sa, 16);   sa  += __shfl_xor(sa, 32);
            qa2 += __shfl_xor(qa2, 16);  qa2 += __shfl_xor(qa2, 32);
            if (lc == 0)
                *reinterpret_cast<float2*>(&red[((it * 16 + lr) * 4 + w) * 2]) =
                    make_float2(sa, qa2);
            if (valid) {
                #pragma unroll
                for (int et = 0; et < 2; ++et)
                    *reinterpret_cast<float4*>(&ost[(it * 16 + lr) * OSTR + h * 32 + et * 16 + 4 * lc]) = yv[et];
            }
        }
        __syncthreads();                                   // B2: red + ost ready

        // ---- read-pass: stats from red (broadcast), LN affine, coalesced store ----
        const int c4r = t & 31;
        const float4 gvr = *reinterpret_cast<const float4*>(&ln_g[d * 128 + c4r * 4]);
        const float4 bvr = *reinterpret_cast<const float4*>(&ln_b[d * 128 + c4r * 4]);
        const size_t b4 = (s0 + s) * 1280;
        #pragma unroll
        for (int j5 = 0; j5 < 5; ++j5) {
            const int idx = j5 * 256 + t;
            const int row = idx >> 5;                      // (idx & 31) == c4r
            const float4 r01 = *reinterpret_cast<const float4*>(&red[row * 8]);
            const float4 r23 = *reinterpret_cast<const float4*>(&red[row * 8 + 4]);
            const float sa = r01.x + r01.z + r23.x + r23.z;
            const float q2 = r01.y + r01.w + r23.y + r23.w;
            const float mean = sa * (1.f / 128.f);
            const float rstd = rsqrtf(q2 * (1.f / 128.f) - mean * mean + 1e-6f);
            const float4 v = *reinterpret_cast<const float4*>(&ost[row * OSTR + c4r * 4]);
            float4 ov;
            ov.x = (v.x - mean) * rstd * gvr.x + bvr.x;
            ov.y = (v.y - mean) * rstd * gvr.y + bvr.y;
            ov.z = (v.z - mean) * rstd * gvr.z + bvr.z;
            ov.w = (v.w - mean) * rstd * gvr.w + bvr.w;
            out4g[b4 + idx] = ov;
        }
    }
}

extern "C" void kernel_launch(void* const* d_in, const int* in_sizes, int n_in,
                              void* d_out, int out_size, void* d_ws, size_t ws_size,
                              hipStream_t stream)
{
    const float* inputs = (const float*)d_in[0];
    const int*   dm     = (const int*)d_in[1];
    const float* Wq     = (const float*)d_in[2];
    const float* Wv     = (const float*)d_in[3];
    const float* Wr     = (const float*)d_in[4];
    const float* g      = (const float*)d_in[5];
    const float* bt     = (const float*)d_in[6];
    float* outp         = (float*)d_out;
    ushort* Wt          = (ushort*)d_ws;   // 6*128*128*2 = 192 KB

    convert_w<<<(6 * 16384 + 255) / 256, 256, 0, stream>>>(Wq, Wv, Wr, Wt);
    mdr_fused13<<<NBLK, NT, 0, stream>>>(inputs, dm, Wt, g, bt, outp);
}